// Round 1
// baseline (2434.617 us; speedup 1.0000x reference)
//
#include <hip/hip_runtime.h>
#include <hip/hip_bf16.h>
#include <math.h>

#define DEV __device__ __forceinline__

typedef __attribute__((ext_vector_type(8))) short short8;
typedef __attribute__((ext_vector_type(4))) float f32x4;

static constexpr int Bsz  = 1024;
static constexpr int T    = 100;
static constexpr int TM1  = 99;
static constexpr int IN   = 64;
static constexpr int H    = 512;
static constexpr int OUTD = 64;
static constexpr int H2   = 1024;
static constexpr int BT   = Bsz * T;        // 102400
static constexpr int NCHUNK = 8;
static constexpr int CROWS  = BT / NCHUNK;  // 12800

DEV unsigned short f2bf(float f){
  unsigned int u = __float_as_uint(f);
  u += 0x7fffu + ((u >> 16) & 1u);          // round-to-nearest-even
  return (unsigned short)(u >> 16);
}
DEV float tanh_fast(float x){
  x = fminf(fmaxf(x, -15.f), 15.f);
  float e = __expf(2.f * x);
  return (e - 1.f) / (e + 1.f);
}

// Stage a 64x64 bf16 tile (row-major src, element stride `stride`) into LDS [64][80].
DEV void stage64(const unsigned short* __restrict__ src, int stride, int row0, int col0,
                 unsigned short (*lds)[80], int tid){
  int r = tid >> 3, cg = tid & 7;           // 32 rows/round, 8 cols-of-8 per row
  *(uint4*)(&lds[r][cg*8])      = *(const uint4*)(src + (size_t)(row0 + r)      * stride + col0 + cg*8);
  *(uint4*)(&lds[r + 32][cg*8]) = *(const uint4*)(src + (size_t)(row0 + r + 32) * stride + col0 + cg*8);
}

// Stage a 64x64 f32 tile, applying tanh and converting to bf16.
DEV void stage_tanh(const float* __restrict__ src, int stride, int row0, int col0,
                    unsigned short (*lds)[80], int tid){
  int r = tid >> 4, cg = tid & 15;          // 16 rows/round, 16 cols-of-4
  #pragma unroll
  for (int rr = 0; rr < 4; rr++){
    int row = rr*16 + r;
    float4 v = *(const float4*)(src + (size_t)(row0 + row) * stride + col0 + cg*4);
    ushort4 o;
    o.x = f2bf(tanh_fast(v.x)); o.y = f2bf(tanh_fast(v.y));
    o.z = f2bf(tanh_fast(v.z)); o.w = f2bf(tanh_fast(v.w));
    *(ushort4*)(&lds[row][cg*4]) = o;
  }
}

// One 64x64x64 chunk: C[m][n] += A[m][k] * B[n][k]  (both LDS tiles are [rows][k])
DEV void mfma_tile(const unsigned short (*As)[80], const unsigned short (*Bs)[80],
                   f32x4 acc[2][2], int wr, int wc, int fr, int fq){
  #pragma unroll
  for (int kk = 0; kk < 64; kk += 32){
    short8 a0 = *(const short8*)(&As[wr*32 + fr     ][kk + fq*8]);
    short8 a1 = *(const short8*)(&As[wr*32 + 16 + fr][kk + fq*8]);
    short8 b0 = *(const short8*)(&Bs[wc*32 + fr     ][kk + fq*8]);
    short8 b1 = *(const short8*)(&Bs[wc*32 + 16 + fr][kk + fq*8]);
    acc[0][0] = __builtin_amdgcn_mfma_f32_16x16x32_bf16(a0, b0, acc[0][0], 0, 0, 0);
    acc[0][1] = __builtin_amdgcn_mfma_f32_16x16x32_bf16(a0, b1, acc[0][1], 0, 0, 0);
    acc[1][0] = __builtin_amdgcn_mfma_f32_16x16x32_bf16(a1, b0, acc[1][0], 0, 0, 0);
    acc[1][1] = __builtin_amdgcn_mfma_f32_16x16x32_bf16(a1, b1, acc[1][1], 0, 0, 0);
  }
}

// ---- prep: transpose all weight matrices to bf16 [N][K] panels (one launch, blockIdx.z = job)
__global__ __launch_bounds__(256) void k_prep(const float* __restrict__ Wf1, const float* __restrict__ Wg1,
                                              const float* __restrict__ Wf2, const float* __restrict__ Wg2,
                                              const float* __restrict__ Wl1, const float* __restrict__ Wl2,
                                              unsigned short* __restrict__ W1T, unsigned short* __restrict__ W2T,
                                              unsigned short* __restrict__ Wl1T, unsigned short* __restrict__ Wl2T){
  __shared__ float tl[32][33];
  const float* src; unsigned short* dst; int N;
  switch (blockIdx.z){
    case 0: src = Wf1; dst = W1T;             N = 512; break;
    case 1: src = Wg1; dst = W1T + 512*512;   N = 512; break;
    case 2: src = Wf2; dst = W2T;             N = 512; break;
    case 3: src = Wg2; dst = W2T + 512*512;   N = 512; break;
    case 4: src = Wl1; dst = Wl1T;            N = 512; break;
    default: src = Wl2; dst = Wl2T;           N = 64;  break;
  }
  int k0 = blockIdx.x*32, n0 = blockIdx.y*32;
  if (n0 >= N) return;                        // block-uniform
  int tx = threadIdx.x, ty = threadIdx.y;     // block (32,8)
  #pragma unroll
  for (int r = 0; r < 4; r++) tl[ty + r*8][tx] = src[(size_t)(k0 + ty + r*8) * N + n0 + tx];
  __syncthreads();
  #pragma unroll
  for (int r = 0; r < 4; r++) dst[(size_t)(n0 + ty + r*8) * 512 + k0 + tx] = f2bf(tl[tx][ty + r*8]);
}

// ---- init: y0 = x0 @ W_init + b_init  (naive f32; K=64, trivial)
__global__ __launch_bounds__(256) void k0_init(const float* __restrict__ coeffs, const float* __restrict__ Wi,
                                               const float* __restrict__ bi,
                                               float* __restrict__ y, unsigned short* __restrict__ yb,
                                               float* __restrict__ z){
  int g = blockIdx.x*256 + threadIdx.x;       // 0 .. B*H-1
  int b = g >> 9, j = g & (H - 1);
  const float* x0 = coeffs + (size_t)b * (TM1 * 4 * IN);   // coeffs[b,0,0,:]
  float s = bi[j];
  #pragma unroll 4
  for (int k = 0; k < IN; k++) s += x0[k] * Wi[(size_t)k * H + j];
  y[g] = s;
  yb[g] = f2bf(s);
  z[(size_t)b * (T * H) + j] = s;             // z[b,0,:]
}

// ---- stage A: u = tanh(y @ [Wf1|Wg1] + [bf1|bg1])   (1024 x 1024 bf16)
__global__ __launch_bounds__(256) void k1_step(const unsigned short* __restrict__ yb,
                                               const unsigned short* __restrict__ W1T,
                                               const float* __restrict__ bf1, const float* __restrict__ bg1,
                                               unsigned short* __restrict__ u){
  __shared__ __align__(16) unsigned short As[64][80], Bs[64][80];
  int tid = threadIdx.x, lane = tid & 63, wid = tid >> 6;
  int wr = wid >> 1, wc = wid & 1, fr = lane & 15, fq = lane >> 4;
  int m0 = blockIdx.x*64, n0 = blockIdx.y*64;
  f32x4 acc[2][2];
  #pragma unroll
  for (int m = 0; m < 2; m++)
    #pragma unroll
    for (int n = 0; n < 2; n++) acc[m][n] = (f32x4){0.f, 0.f, 0.f, 0.f};
  for (int kc = 0; kc < H; kc += 64){
    __syncthreads();
    stage64(yb,  H, m0, kc, As, tid);
    stage64(W1T, H, n0, kc, Bs, tid);
    __syncthreads();
    mfma_tile(As, Bs, acc, wr, wc, fr, fq);
  }
  const float* bias = (n0 < 512) ? bf1 : bg1;
  int bo = (n0 < 512) ? 0 : 512;
  #pragma unroll
  for (int m = 0; m < 2; m++)
    #pragma unroll
    for (int n = 0; n < 2; n++)
      #pragma unroll
      for (int r = 0; r < 4; r++){
        int row = m0 + wr*32 + m*16 + fq*4 + r;
        int col = n0 + wc*32 + n*16 + fr;
        float v = acc[m][n][r] + bias[col - bo];
        u[(size_t)row * H2 + col] = f2bf(tanh_fast(v));
      }
}

// ---- stage B: y += (u_f@Wf2+bf2)*h + tanh(u_g@Wg2+bg2)*(sqrt(h)*dW);  write z[:,t+1,:]
__global__ __launch_bounds__(256) void k2_step(const unsigned short* __restrict__ u,
                                               const unsigned short* __restrict__ W2T,
                                               const float* __restrict__ bf2, const float* __restrict__ bg2,
                                               const float* __restrict__ dWt,
                                               const float* __restrict__ times, int t,
                                               float* __restrict__ y, unsigned short* __restrict__ yb,
                                               float* __restrict__ z){
  __shared__ __align__(16) unsigned short Af[64][80], Ag[64][80], Bf[64][80], Bg[64][80];
  int tid = threadIdx.x, lane = tid & 63, wid = tid >> 6;
  int wr = wid >> 1, wc = wid & 1, fr = lane & 15, fq = lane >> 4;
  int m0 = blockIdx.x*64, n0 = blockIdx.y*64;
  f32x4 accf[2][2], accg[2][2];
  #pragma unroll
  for (int m = 0; m < 2; m++)
    #pragma unroll
    for (int n = 0; n < 2; n++){ accf[m][n] = (f32x4){0.f,0.f,0.f,0.f}; accg[m][n] = (f32x4){0.f,0.f,0.f,0.f}; }
  for (int kc = 0; kc < H; kc += 64){
    __syncthreads();
    stage64(u,   H2, m0, kc,        Af, tid);
    stage64(u,   H2, m0, 512 + kc,  Ag, tid);
    stage64(W2T, H,  n0, kc,        Bf, tid);
    stage64(W2T, H,  512 + n0, kc,  Bg, tid);
    __syncthreads();
    mfma_tile(Af, Bf, accf, wr, wc, fr, fq);
    mfma_tile(Ag, Bg, accg, wr, wc, fr, fq);
  }
  float h = times[t + 1] - times[t];
  float sq = sqrtf(h);
  #pragma unroll
  for (int m = 0; m < 2; m++)
    #pragma unroll
    for (int n = 0; n < 2; n++)
      #pragma unroll
      for (int r = 0; r < 4; r++){
        int row = m0 + wr*32 + m*16 + fq*4 + r;
        int col = n0 + wc*32 + n*16 + fr;
        size_t idx = (size_t)row * H + col;
        float fv = accf[m][n][r] + bf2[col];
        float gv = tanh_fast(accg[m][n][r] + bg2[col]);
        float yn = y[idx] + fv * h + gv * (sq * dWt[idx]);
        y[idx] = yn;
        yb[idx] = f2bf(yn);
        z[(size_t)row * (T * H) + (size_t)(t + 1) * H + col] = yn;
      }
}

// ---- readout G1 (chunked): rel = relu(tanh(z_chunk) @ Wl1 + bl1)  -> bf16
__global__ __launch_bounds__(256) void k3a(const float* __restrict__ zc,
                                           const unsigned short* __restrict__ Wl1T,
                                           const float* __restrict__ bl1,
                                           unsigned short* __restrict__ rel){
  __shared__ __align__(16) unsigned short As[64][80], Bs[64][80];
  int tid = threadIdx.x, lane = tid & 63, wid = tid >> 6;
  int wr = wid >> 1, wc = wid & 1, fr = lane & 15, fq = lane >> 4;
  int m0 = blockIdx.x*64, n0 = blockIdx.y*64;
  f32x4 acc[2][2];
  #pragma unroll
  for (int m = 0; m < 2; m++)
    #pragma unroll
    for (int n = 0; n < 2; n++) acc[m][n] = (f32x4){0.f,0.f,0.f,0.f};
  for (int kc = 0; kc < H; kc += 64){
    __syncthreads();
    stage_tanh(zc,  H, m0, kc, As, tid);
    stage64(Wl1T,   H, n0, kc, Bs, tid);
    __syncthreads();
    mfma_tile(As, Bs, acc, wr, wc, fr, fq);
  }
  #pragma unroll
  for (int m = 0; m < 2; m++)
    #pragma unroll
    for (int n = 0; n < 2; n++)
      #pragma unroll
      for (int r = 0; r < 4; r++){
        int row = m0 + wr*32 + m*16 + fq*4 + r;
        int col = n0 + wc*32 + n*16 + fr;
        float v = acc[m][n][r] + bl1[col];
        rel[(size_t)row * H + col] = f2bf(fmaxf(v, 0.f));
      }
}

// ---- readout G2 (chunked): out = rel @ Wl2 + bl2  (N = 64)
__global__ __launch_bounds__(256) void k3b(const unsigned short* __restrict__ rel,
                                           const unsigned short* __restrict__ Wl2T,
                                           const float* __restrict__ bl2,
                                           float* __restrict__ outc){
  __shared__ __align__(16) unsigned short As[64][80], Bs[64][80];
  int tid = threadIdx.x, lane = tid & 63, wid = tid >> 6;
  int wr = wid >> 1, wc = wid & 1, fr = lane & 15, fq = lane >> 4;
  int m0 = blockIdx.x*64;
  f32x4 acc[2][2];
  #pragma unroll
  for (int m = 0; m < 2; m++)
    #pragma unroll
    for (int n = 0; n < 2; n++) acc[m][n] = (f32x4){0.f,0.f,0.f,0.f};
  for (int kc = 0; kc < H; kc += 64){
    __syncthreads();
    stage64(rel,  H, m0, kc, As, tid);
    stage64(Wl2T, H, 0,  kc, Bs, tid);
    __syncthreads();
    mfma_tile(As, Bs, acc, wr, wc, fr, fq);
  }
  #pragma unroll
  for (int m = 0; m < 2; m++)
    #pragma unroll
    for (int n = 0; n < 2; n++)
      #pragma unroll
      for (int r = 0; r < 4; r++){
        int row = m0 + wr*32 + m*16 + fq*4 + r;
        int col = wc*32 + n*16 + fr;           // 0..63
        outc[(size_t)row * OUTD + col] = acc[m][n][r] + bl2[col];
      }
}

extern "C" void kernel_launch(void* const* d_in, const int* in_sizes, int n_in,
                              void* d_out, int out_size, void* d_ws, size_t ws_size,
                              hipStream_t stream){
  (void)in_sizes; (void)n_in; (void)out_size; (void)ws_size;
  const float* coeffs = (const float*)d_in[0];
  const float* times  = (const float*)d_in[1];
  const float* dW     = (const float*)d_in[2];
  const float* W_init = (const float*)d_in[3];
  const float* b_init = (const float*)d_in[4];
  const float* Wf1 = (const float*)d_in[5];
  const float* bf1 = (const float*)d_in[6];
  const float* Wf2 = (const float*)d_in[7];
  const float* bf2 = (const float*)d_in[8];
  const float* Wg1 = (const float*)d_in[9];
  const float* bg1 = (const float*)d_in[10];
  const float* Wg2 = (const float*)d_in[11];
  const float* bg2 = (const float*)d_in[12];
  const float* Wl1 = (const float*)d_in[13];
  const float* bl1 = (const float*)d_in[14];
  const float* Wl2 = (const float*)d_in[15];
  const float* bl2 = (const float*)d_in[16];

  float* out = (float*)d_out;
  float* z   = out + (size_t)Bsz * T * OUTD;   // z region of d_out, (B,T,H) row-major

  char* w = (char*)d_ws;
  auto carve = [&](size_t bytes) -> void* {
    void* p = (void*)w; w += (bytes + 255) & ~(size_t)255; return p;
  };
  float*          y    = (float*)carve((size_t)Bsz * H * 4);
  unsigned short* yb   = (unsigned short*)carve((size_t)Bsz * H * 2);
  unsigned short* u    = (unsigned short*)carve((size_t)Bsz * H2 * 2);
  unsigned short* W1T  = (unsigned short*)carve((size_t)H2 * H * 2);
  unsigned short* W2T  = (unsigned short*)carve((size_t)H2 * H * 2);
  unsigned short* Wl1T = (unsigned short*)carve((size_t)H * H * 2);
  unsigned short* Wl2T = (unsigned short*)carve((size_t)OUTD * H * 2);
  unsigned short* rel  = (unsigned short*)carve((size_t)CROWS * H * 2);

  k_prep<<<dim3(16, 16, 6), dim3(32, 8), 0, stream>>>(Wf1, Wg1, Wf2, Wg2, Wl1, Wl2,
                                                      W1T, W2T, Wl1T, Wl2T);
  k0_init<<<dim3(Bsz * H / 256), 256, 0, stream>>>(coeffs, W_init, b_init, y, yb, z);

  for (int t = 0; t < TM1; t++){
    k1_step<<<dim3(16, 16), 256, 0, stream>>>(yb, W1T, bf1, bg1, u);
    k2_step<<<dim3(16, 8), 256, 0, stream>>>(u, W2T, bf2, bg2,
                                             dW + (size_t)t * Bsz * H, times, t, y, yb, z);
  }
  for (int c = 0; c < NCHUNK; c++){
    k3a<<<dim3(CROWS / 64, 8), 256, 0, stream>>>(z + (size_t)c * CROWS * H, Wl1T, bl1, rel);
    k3b<<<dim3(CROWS / 64, 1), 256, 0, stream>>>(rel, Wl2T, bl2, out + (size_t)c * CROWS * OUTD);
  }
}